// Round 4
// baseline (814.560 us; speedup 1.0000x reference)
//
#include <hip/hip_runtime.h>

#define T_DIM 2048
#define D_DIM 256
#define K_CODES 512
#define N_ROWS 131072
#define Q_ELEMS 33554432
#define MARGIN 8e-4f

typedef __attribute__((ext_vector_type(8))) short bf16x8;
typedef __attribute__((ext_vector_type(4))) float f32x4;

// ws layout (bytes):
// [0, 2048)        norms (512 f32, numpy-pairwise-exact)
// [2048, 10240)    bsums (1024 f64)
// [12288, 28672)   flag bitmap (4096 u32 = 131072 bits)
// [32768, 294912)  e_ws bf16 tiled [kc:2][kh:4][code:256][swizzled 64-k]  (only if ws fits)

__device__ __forceinline__ float comb8(const float r[8]) {
  return ((r[0] + r[1]) + (r[2] + r[3])) + ((r[4] + r[5]) + (r[6] + r[7]));
}

__device__ __forceinline__ unsigned short f2bf(float f) {
  unsigned u = __float_as_uint(f);
  unsigned r = (u + 0x7FFFu + ((u >> 16) & 1u)) >> 16;
  return (unsigned short)r;
}

__device__ __forceinline__ void gl_lds16(const void* g, void* l) {
  __builtin_amdgcn_global_load_lds(
      (const __attribute__((address_space(1))) unsigned int*)g,
      (__attribute__((address_space(3))) unsigned int*)l, 16, 0, 0);
}

// One block per code k: norms (numpy pairwise), e_ws swizzled bf16, bitmap zero.
__global__ __launch_bounds__(256) void vq_prep(const float* __restrict__ e,
                                               float* __restrict__ norms,
                                               unsigned short* __restrict__ e_ws,
                                               unsigned* __restrict__ bitmap,
                                               int use_ws) {
  __shared__ float srow[D_DIM];
  int k = blockIdx.x, t = threadIdx.x;
  float v = e[k * D_DIM + t];
  srow[t] = v;
  if (use_ws) {
    int kc = k >> 8, cl = k & 255, kh = t >> 6, kl = t & 63;
    int slot = (kl >> 3) ^ (cl & 7);
    e_ws[kc * 65536 + kh * 16384 + cl * 64 + slot * 8 + (kl & 7)] = f2bf(v);
  }
  if (t < 8) bitmap[k * 8 + t] = 0u;
  __syncthreads();
  if (t == 0) {
    float res[2];
    #pragma unroll
    for (int h = 0; h < 2; ++h) {
      float r[8];
      #pragma unroll
      for (int j = 0; j < 8; ++j) { float a = srow[h * 128 + j]; r[j] = __fmul_rn(a, a); }
      for (int i = 8; i < 128; i += 8)
        #pragma unroll
        for (int j = 0; j < 8; ++j) { float a = srow[h * 128 + i + j]; r[j] = __fadd_rn(r[j], __fmul_rn(a, a)); }
      res[h] = comb8(r);
    }
    norms[k] = __fadd_rn(res[0], res[1]);
  }
}

template <int USE_WS>
__global__ __launch_bounds__(256, 1) void vq_main(
    const float* __restrict__ x, const float* __restrict__ e,
    const float* __restrict__ norms, const unsigned short* __restrict__ e_ws,
    float* __restrict__ out_q, float* __restrict__ out_idx,
    double* __restrict__ bsums, unsigned* __restrict__ bitmap) {
  __shared__ unsigned short xlds[128 * 256];    // 64 KB, chunk-swizzled
  __shared__ unsigned short blds[2][256 * 64];  // 2 x 32 KB
  __shared__ float nlds[K_CODES];
  __shared__ float wminS[2][128];
  __shared__ int   widS[2][128];
  __shared__ int   wcntS[2][128];
  __shared__ float rmin[128];
  __shared__ int   widx[128];
  __shared__ unsigned lflag[4];
  __shared__ double dred[4];

  const int tx = threadIdx.x;
  const int blk = blockIdx.x;                 // 1024
  const int b = blk >> 4, t0 = (blk & 15) * 128;
  const int lane = tx & 63, w = tx >> 6;
  const int wm = w & 1, wn = w >> 1;          // wave tile: rows wm*64, codes wn*128
  const int c = lane & 15, g = lane >> 4;     // frag col / k-subgroup

  nlds[tx] = norms[tx];
  nlds[tx + 256] = norms[tx + 256];
  if (tx < 4) lflag[tx] = 0u;

  if (USE_WS) {  // issue B stage 0 early (overlaps x conversion)
    #pragma unroll
    for (int i = 0; i < 8; ++i)
      gl_lds16(e_ws + i * 2048 + tx * 8, &blds[0][i * 2048 + w * 512]);
  }

  // stage x: fp32 -> bf16 swizzled LDS, accumulate sum(x^2)
  float xsum = 0.f;
  {
    const int dgrp = tx >> 5, f4 = tx & 31;
    const float* xb = x + (size_t)b * (D_DIM * T_DIM) + t0 + f4 * 4;
    for (int p = 0; p < 32; ++p) {
      int d = p * 8 + dgrp;
      float4 v = *(const float4*)(xb + (size_t)d * T_DIM);
      int chunk = d >> 3, dl = d & 7;
      float vv[4] = {v.x, v.y, v.z, v.w};
      #pragma unroll
      for (int j = 0; j < 4; ++j) {
        int row = f4 * 4 + j;
        int slot = (chunk & 24) | ((chunk ^ row) & 7);
        xlds[row * 256 + slot * 8 + dl] = f2bf(vv[j]);
        xsum = fmaf(vv[j], vv[j], xsum);
      }
    }
  }
  if (!USE_WS) {  // fallback: stage 0 B from e directly (fp32 -> bf16 -> LDS)
    const float* src = e + (size_t)tx * D_DIM;  // code tx, kc=0 kh=0 -> d 0..63
    #pragma unroll
    for (int ch = 0; ch < 8; ++ch) {
      float4 v0 = *(const float4*)(src + ch * 8);
      float4 v1 = *(const float4*)(src + ch * 8 + 4);
      unsigned short u[8] = {f2bf(v0.x), f2bf(v0.y), f2bf(v0.z), f2bf(v0.w),
                             f2bf(v1.x), f2bf(v1.y), f2bf(v1.z), f2bf(v1.w)};
      int slot = ch ^ (tx & 7);
      *(bf16x8*)&blds[0][tx * 64 + slot * 8] = *(bf16x8*)u;
    }
  }
  if (USE_WS) asm volatile("s_waitcnt vmcnt(0)");
  __syncthreads();

  f32x4 acc[4][8];
  #pragma unroll
  for (int mi = 0; mi < 4; ++mi)
    #pragma unroll
    for (int nj = 0; nj < 8; ++nj) acc[mi][nj] = (f32x4){0.f, 0.f, 0.f, 0.f};

  float mrow[4][4];
  int irow[4][4], crow[4][4];
  #pragma unroll
  for (int mi = 0; mi < 4; ++mi)
    #pragma unroll
    for (int q = 0; q < 4; ++q) { mrow[mi][q] = 3.4e38f; irow[mi][q] = 0; crow[mi][q] = 1; }

  for (int s = 0; s < 8; ++s) {
    if (s < 7) {  // prefetch stage s+1 into other buffer
      int s1 = s + 1;
      if (USE_WS) {
        const unsigned short* src = e_ws + (s1 >> 2) * 65536 + (s1 & 3) * 16384;
        #pragma unroll
        for (int i = 0; i < 8; ++i)
          gl_lds16(src + i * 2048 + tx * 8, &blds[s1 & 1][i * 2048 + w * 512]);
      } else {
        const float* src = e + (size_t)((s1 >> 2) * 256 + tx) * D_DIM + (s1 & 3) * 64;
        #pragma unroll
        for (int ch = 0; ch < 8; ++ch) {
          float4 v0 = *(const float4*)(src + ch * 8);
          float4 v1 = *(const float4*)(src + ch * 8 + 4);
          unsigned short u[8] = {f2bf(v0.x), f2bf(v0.y), f2bf(v0.z), f2bf(v0.w),
                                 f2bf(v1.x), f2bf(v1.y), f2bf(v1.z), f2bf(v1.w)};
          int slot = ch ^ (tx & 7);
          *(bf16x8*)&blds[s1 & 1][tx * 64 + slot * 8] = *(bf16x8*)u;
        }
      }
    }
    const unsigned short* bbuf = &blds[s & 1][0];
    const int kh = s & 3;
    #pragma unroll
    for (int ks2 = 0; ks2 < 2; ++ks2) {
      bf16x8 af[4], bf[8];
      #pragma unroll
      for (int mi = 0; mi < 4; ++mi) {
        int rl = wm * 64 + mi * 16 + c;
        int chunk = kh * 8 + ks2 * 4 + g;
        int slot = (chunk & 24) | ((chunk ^ rl) & 7);
        af[mi] = *(const bf16x8*)&xlds[rl * 256 + slot * 8];
      }
      #pragma unroll
      for (int nj = 0; nj < 8; ++nj) {
        int cr = wn * 128 + nj * 16 + c;
        int slot = (ks2 * 4 + g) ^ (cr & 7);
        bf[nj] = *(const bf16x8*)&bbuf[cr * 64 + slot * 8];
      }
      #pragma unroll
      for (int mi = 0; mi < 4; ++mi)
        #pragma unroll
        for (int nj = 0; nj < 8; ++nj)
          acc[mi][nj] = __builtin_amdgcn_mfma_f32_16x16x32_bf16(af[mi], bf[nj], acc[mi][nj], 0, 0, 0);
    }
    if ((s & 3) == 3) {  // end of kc: fold scores into running argmin+margin state
      int kc = s >> 2;
      float nrm[8];
      #pragma unroll
      for (int nj = 0; nj < 8; ++nj) nrm[nj] = nlds[kc * 256 + wn * 128 + nj * 16 + c];
      #pragma unroll
      for (int mi = 0; mi < 4; ++mi)
        #pragma unroll
        for (int q = 0; q < 4; ++q) {
          float m = mrow[mi][q]; int id = irow[mi][q]; int cn = crow[mi][q];
          #pragma unroll
          for (int nj = 0; nj < 8; ++nj) {
            float sv = fmaf(-2.f, acc[mi][nj][q], nrm[nj]);
            int code = kc * 256 + wn * 128 + nj * 16 + c;
            if (sv < m - MARGIN)      { m = sv; id = code; cn = 1; }
            else if (sv < m)          { m = sv; id = code; cn++; }
            else if (sv <= m + MARGIN) cn++;
          }
          mrow[mi][q] = m; irow[mi][q] = id; crow[mi][q] = cn;
        }
      #pragma unroll
      for (int mi = 0; mi < 4; ++mi)
        #pragma unroll
        for (int nj = 0; nj < 8; ++nj) acc[mi][nj] = (f32x4){0.f, 0.f, 0.f, 0.f};
    }
    if (USE_WS) asm volatile("s_waitcnt vmcnt(0)");
    __syncthreads();
  }

  // cross-lane reduce within 16-lane groups (same rows, 16 code-cols)
  #pragma unroll
  for (int mi = 0; mi < 4; ++mi)
    #pragma unroll
    for (int q = 0; q < 4; ++q) {
      float m = mrow[mi][q]; int id = irow[mi][q]; int cn = crow[mi][q];
      #pragma unroll
      for (int off = 1; off < 16; off <<= 1) {
        float om = __shfl_xor(m, off, 64);
        int oi = __shfl_xor(id, off, 64);
        int oc = __shfl_xor(cn, off, 64);
        int nc;
        if (om < m - MARGIN) nc = oc;
        else if (m < om - MARGIN) nc = cn;
        else nc = cn + oc;
        if (om < m || (om == m && oi < id)) { m = om; id = oi; }
        cn = nc;
      }
      if (c == 0) {
        int rl = wm * 64 + mi * 16 + g * 4 + q;
        wminS[wn][rl] = m; widS[wn][rl] = id; wcntS[wn][rl] = cn;
      }
    }
  __syncthreads();
  // merge the two code-half waves per row
  if (tx < 128) {
    float m0 = wminS[0][tx], m1 = wminS[1][tx];
    int i0 = widS[0][tx], i1 = widS[1][tx];
    int c0 = wcntS[0][tx], c1 = wcntS[1][tx];
    int cn = (fabsf(m0 - m1) <= MARGIN) ? (c0 + c1) : ((m1 < m0) ? c1 : c0);
    float m; int id;
    if (m1 < m0 || (m1 == m0 && i1 < i0)) { m = m1; id = i1; } else { m = m0; id = i0; }
    widx[tx] = id; rmin[tx] = m;
    out_idx[(size_t)blk * 128 + tx] = (float)id;
    if (cn >= 2) atomicOr(&lflag[tx >> 5], 1u << (tx & 31));
  }
  __syncthreads();
  if (tx < 4) bitmap[blk * 4 + tx] = lflag[tx];

  // fused q-write: wave w writes rows [w*32, w*32+32)
  for (int i = 0; i < 32; ++i) {
    int row = w * 32 + i;
    int k = widx[row];
    float4 ev = *(const float4*)(e + (size_t)k * D_DIM + lane * 4);
    *(float4*)(out_q + ((size_t)blk * 128 + row) * D_DIM + lane * 4) = ev;
  }

  // loss partial: sum(x^2) + sum(row min scores)
  double dv = (double)xsum + ((tx < 128) ? (double)rmin[tx] : 0.0);
  #pragma unroll
  for (int o = 32; o > 0; o >>= 1) dv += __shfl_down(dv, o, 64);
  if (lane == 0) dred[w] = dv;
  __syncthreads();
  if (tx == 0) bsums[blk] = (dred[0] + dred[1]) + (dred[2] + dred[3]);
}

// Exact fp32 rescan (numpy-replica, round-2-validated formulas) for flagged rows.
__global__ __launch_bounds__(256) void vq_fixup(
    const float* __restrict__ x, const float* __restrict__ e,
    const float* __restrict__ norms, const unsigned* __restrict__ bitmap,
    float* __restrict__ out_q, float* __restrict__ out_idx) {
  __shared__ float xrow[16][257];
  __shared__ float elds[64][257];
  __shared__ float xxr[16];
  __shared__ int list[256];
  __shared__ int lcount;
  __shared__ float redm[16][16];
  __shared__ int   redi[16][16];
  __shared__ int   wk[16];

  const int bidx = blockIdx.x, tx = threadIdx.x;
  if (tx == 0) {
    int cnt = 0;
    for (int wi = 0; wi < 8; ++wi) {
      unsigned u = bitmap[bidx * 8 + wi];
      while (u) {
        int bit = __ffs(u) - 1;
        list[cnt++] = bidx * 256 + wi * 32 + bit;
        u &= u - 1;
      }
    }
    lcount = cnt;
  }
  __syncthreads();
  const int nf = lcount;
  const int ri = tx >> 4, dpart = tx & 15;
  const int r = tx & 15, cg = tx >> 4;

  for (int g0 = 0; g0 < nf; g0 += 16) {
    int R = min(16, nf - g0);
    if (ri < R) {
      int n = list[g0 + ri];
      int b2 = n >> 11, t = n & 2047;
      for (int j = 0; j < 16; ++j) {
        int d = dpart * 16 + j;
        xrow[ri][d] = x[((size_t)(b2 * 256 + d)) * 2048 + t];
      }
    }
    __syncthreads();
    if (tx < R) {  // numpy-pairwise ||x||^2
      float res[2];
      #pragma unroll
      for (int h = 0; h < 2; ++h) {
        float r8[8];
        #pragma unroll
        for (int j = 0; j < 8; ++j) { float a = xrow[tx][h * 128 + j]; r8[j] = __fmul_rn(a, a); }
        for (int i = 8; i < 128; i += 8)
          #pragma unroll
          for (int j = 0; j < 8; ++j) { float a = xrow[tx][h * 128 + i + j]; r8[j] = __fadd_rn(r8[j], __fmul_rn(a, a)); }
        res[h] = comb8(r8);
      }
      xxr[tx] = __fadd_rn(res[0], res[1]);
    }
    float m = 3.4e38f; int mi_ = 0;
    for (int ch = 0; ch < 8; ++ch) {
      __syncthreads();
      {
        int er = tx >> 2, qd = tx & 3;
        for (int j = 0; j < 16; ++j)
          *(float4*)&elds[er][qd * 64 + j * 4] =
              *(const float4*)(e + (size_t)(ch * 64 + er) * 256 + qd * 64 + j * 4);
      }
      __syncthreads();
      if (r < R) {
        for (int j = 0; j < 4; ++j) {
          int kl = cg * 4 + j;
          float a = 0.f;
          for (int d = 0; d < 256; ++d) a = __fmaf_rn(xrow[r][d], elds[kl][d], a);
          int k = ch * 64 + kl;
          float t1 = __fadd_rn(xxr[r], norms[k]);
          float sv = t1 - 2.0f * a;
          if (sv < m) { m = sv; mi_ = k; }
        }
      }
    }
    redm[r][cg] = m; redi[r][cg] = mi_;
    __syncthreads();
    if (tx < R) {
      float mm = redm[tx][0]; int ii = redi[tx][0];
      for (int q2 = 1; q2 < 16; ++q2) {
        float s2 = redm[tx][q2]; int s2i = redi[tx][q2];
        if (s2 < mm || (s2 == mm && s2i < ii)) { mm = s2; ii = s2i; }
      }
      int n = list[g0 + tx];
      out_idx[n] = (float)ii;
      wk[tx] = ii;
    }
    __syncthreads();
    if (ri < R) {
      int n = list[g0 + ri];
      int k = wk[ri];
      for (int j = 0; j < 16; ++j) {
        int d = dpart * 16 + j;
        out_q[(size_t)n * 256 + d] = e[(size_t)k * 256 + d];
      }
    }
    __syncthreads();
  }
}

__global__ __launch_bounds__(256) void vq_final(const double* __restrict__ bs,
                                                float* __restrict__ out_loss) {
  __shared__ double sred[4];
  int t = threadIdx.x;
  double s = 0.0;
  for (int i = t; i < 1024; i += 256) s += bs[i];
  #pragma unroll
  for (int o = 32; o > 0; o >>= 1) s += __shfl_down(s, o, 64);
  if ((t & 63) == 0) sred[t >> 6] = s;
  __syncthreads();
  if (t == 0)
    out_loss[0] = (float)(0.25 * (((sred[0] + sred[1]) + (sred[2] + sred[3])) / (double)Q_ELEMS));
}

extern "C" void kernel_launch(void* const* d_in, const int* in_sizes, int n_in,
                              void* d_out, int out_size, void* d_ws, size_t ws_size,
                              hipStream_t stream) {
  const float* x = (const float*)d_in[0];
  const float* e = (const float*)d_in[1];
  float* out = (float*)d_out;
  float* out_q = out;
  float* out_loss = out + Q_ELEMS;
  float* out_idx = out + Q_ELEMS + 1;

  char* ws = (char*)d_ws;
  float* norms = (float*)ws;
  double* bsums = (double*)(ws + 2048);
  unsigned* bitmap = (unsigned*)(ws + 12288);
  unsigned short* e_ws = (unsigned short*)(ws + 32768);
  int use_ws = (ws_size >= 294912) ? 1 : 0;

  vq_prep<<<K_CODES, 256, 0, stream>>>(e, norms, e_ws, bitmap, use_ws);
  if (use_ws)
    vq_main<1><<<N_ROWS / 128, 256, 0, stream>>>(x, e, norms, e_ws, out_q, out_idx, bsums, bitmap);
  else
    vq_main<0><<<N_ROWS / 128, 256, 0, stream>>>(x, e, norms, e_ws, out_q, out_idx, bsums, bitmap);
  vq_fixup<<<512, 256, 0, stream>>>(x, e, norms, bitmap, out_q, out_idx);
  vq_final<<<1, 256, 0, stream>>>(bsums, out_loss);
}

// Round 5
// 493.403 us; speedup vs baseline: 1.6509x; 1.6509x over previous
//
#include <hip/hip_runtime.h>

#define T_DIM 2048
#define D_DIM 256
#define K_CODES 512
#define N_ROWS 131072
#define Q_ELEMS 33554432
#define FMARGIN 1.0e-4f

typedef __attribute__((ext_vector_type(8))) short bf16x8;
typedef __attribute__((ext_vector_type(4))) float f32x4;

// ws layout (bytes):
// [0, 2048)        norms (512 f32, numpy-pairwise-exact)
// [2048, 18432)    bsums (2048 f64)
// [20480, 36864)   flag bitmap (4096 u32; word w covers rows w*32..w*32+31)
// [36864, 561152)  e_ws bf16 hi/lo, linear gl_lds image per stage (512 KB)
//   stage s (s = cq*4+kq; cq=code-quarter of 128, kq=k-quarter of 64):
//   u16 idx = s*16384 + var*8192 + cl*64 + slot*8 + (kd&7), slot=(kd>>3)^(cl&7)

__device__ __forceinline__ float comb8(const float r[8]) {
  return ((r[0] + r[1]) + (r[2] + r[3])) + ((r[4] + r[5]) + (r[6] + r[7]));
}

__device__ __forceinline__ unsigned short f2bf(float f) {
  unsigned u = __float_as_uint(f);
  unsigned r = (u + 0x7FFFu + ((u >> 16) & 1u)) >> 16;
  return (unsigned short)r;
}
__device__ __forceinline__ float bf2f(unsigned short h) {
  return __uint_as_float((unsigned)h << 16);
}

__device__ __forceinline__ void gl_lds16(const void* g, void* l) {
  __builtin_amdgcn_global_load_lds(
      (const __attribute__((address_space(1))) unsigned int*)g,
      (__attribute__((address_space(3))) unsigned int*)l, 16, 0, 0);
}

__global__ __launch_bounds__(256) void vq_prep(const float* __restrict__ e,
                                               float* __restrict__ norms,
                                               unsigned short* __restrict__ e_ws,
                                               unsigned* __restrict__ bitmap,
                                               int use_ws) {
  __shared__ float srow[D_DIM];
  int k = blockIdx.x, t = threadIdx.x;
  float v = e[k * D_DIM + t];
  srow[t] = v;
  unsigned short hi = f2bf(v);
  unsigned short lo = f2bf(v - bf2f(hi));
  if (use_ws) {
    int s = (k >> 7) * 4 + (t >> 6);
    int cl = k & 127, kd = t & 63;
    int slot = (kd >> 3) ^ (cl & 7);
    int base = s * 16384 + cl * 64 + slot * 8 + (kd & 7);
    e_ws[base] = hi;
    e_ws[base + 8192] = lo;
  }
  if (t < 8) bitmap[k * 8 + t] = 0u;
  __syncthreads();
  if (t == 0) {
    float res[2];
    #pragma unroll
    for (int h = 0; h < 2; ++h) {
      float r[8];
      #pragma unroll
      for (int j = 0; j < 8; ++j) { float a = srow[h * 128 + j]; r[j] = __fmul_rn(a, a); }
      for (int i = 8; i < 128; i += 8)
        #pragma unroll
        for (int j = 0; j < 8; ++j) { float a = srow[h * 128 + i + j]; r[j] = __fadd_rn(r[j], __fmul_rn(a, a)); }
      res[h] = comb8(r);
    }
    norms[k] = __fadd_rn(res[0], res[1]);
  }
}

template <int USE_WS>
__global__ __launch_bounds__(256, 1) void vq_main(
    const float* __restrict__ x, const float* __restrict__ e,
    const float* __restrict__ norms, const unsigned short* __restrict__ e_ws,
    float* __restrict__ out_q, float* __restrict__ out_idx,
    double* __restrict__ bsums, unsigned* __restrict__ bitmap) {
  __shared__ unsigned short xh[64 * 256];      // 32 KB, chunk-swizzled
  __shared__ unsigned short xl[64 * 256];      // 32 KB
  __shared__ unsigned short bb[2][2][8192];    // 64 KB: [buf][hi/lo][128code x 64k swz]
  __shared__ float nlds[K_CODES];
  __shared__ float wmin[4][64];
  __shared__ int   wid[4][64];
  __shared__ int   wcnt[4][64];
  __shared__ float rmin[64];
  __shared__ int   widx[64];
  __shared__ unsigned lflag[2];
  __shared__ double dred[4];

  const int tx = threadIdx.x;
  const int blk = blockIdx.x;                  // 2048
  const int b = blk >> 5, t0 = (blk & 31) * 64;
  const int lane = tx & 63, w = tx >> 6;
  const int c = lane & 15, g = lane >> 4;
  unsigned short* bbf = &bb[0][0][0];

  nlds[tx] = norms[tx];
  nlds[tx + 256] = norms[tx + 256];
  if (tx < 2) lflag[tx] = 0u;

  if (USE_WS) {  // stage 0 issued early, overlaps x conversion
    #pragma unroll
    for (int i = 0; i < 8; ++i)
      gl_lds16(e_ws + i * 2048 + tx * 8, bbf + i * 2048 + w * 512);
  }

  // stage x: fp32 -> (hi,lo) bf16 swizzled LDS; accumulate sum(x^2)
  float xsum = 0.f;
  {
    const int f4 = tx & 15, drow = tx >> 4;
    const float* xb = x + (size_t)b * (D_DIM * T_DIM) + t0 + f4 * 4;
    #pragma unroll 4
    for (int p = 0; p < 16; ++p) {
      int d = p * 16 + drow;
      float4 v = *(const float4*)(xb + (size_t)d * T_DIM);
      int chunk = d >> 3, dl = d & 7;
      float vv[4] = {v.x, v.y, v.z, v.w};
      #pragma unroll
      for (int j = 0; j < 4; ++j) {
        int row = f4 * 4 + j;
        int slot = (chunk & 24) | ((chunk ^ row) & 7);
        unsigned short hi = f2bf(vv[j]);
        xh[row * 256 + slot * 8 + dl] = hi;
        xl[row * 256 + slot * 8 + dl] = f2bf(vv[j] - bf2f(hi));
        xsum = fmaf(vv[j], vv[j], xsum);
      }
    }
  }
  if (!USE_WS) {  // fallback: stage 0 from e directly
    const int cl = tx & 127, kh2 = tx >> 7;
    const float* src = e + (size_t)cl * D_DIM;  // cq=0, kq=0
    #pragma unroll
    for (int ch8 = 0; ch8 < 4; ++ch8) {
      int kd0 = kh2 * 32 + ch8 * 8;
      float4 v0 = *(const float4*)(src + kd0);
      float4 v1 = *(const float4*)(src + kd0 + 4);
      float vv[8] = {v0.x, v0.y, v0.z, v0.w, v1.x, v1.y, v1.z, v1.w};
      unsigned short h8[8], l8[8];
      #pragma unroll
      for (int j = 0; j < 8; ++j) { h8[j] = f2bf(vv[j]); l8[j] = f2bf(vv[j] - bf2f(h8[j])); }
      int slot = (kd0 >> 3) ^ (cl & 7);
      *(bf16x8*)&bbf[cl * 64 + slot * 8] = *(bf16x8*)h8;
      *(bf16x8*)&bbf[8192 + cl * 64 + slot * 8] = *(bf16x8*)l8;
    }
  }

  f32x4 acc[4][2];
  #pragma unroll
  for (int mi = 0; mi < 4; ++mi)
    #pragma unroll
    for (int nj = 0; nj < 2; ++nj) acc[mi][nj] = (f32x4){0.f, 0.f, 0.f, 0.f};

  float mrow[4][4];
  int irow[4][4], crow[4][4];
  #pragma unroll
  for (int mi = 0; mi < 4; ++mi)
    #pragma unroll
    for (int q = 0; q < 4; ++q) { mrow[mi][q] = 3.4e38f; irow[mi][q] = 0; crow[mi][q] = 1; }

  for (int s = 0; s < 16; ++s) {
    if (s < 15) {  // prefetch stage s+1 into other buffer
      int s1 = s + 1, buf1 = s1 & 1;
      if (USE_WS) {
        #pragma unroll
        for (int i = 0; i < 8; ++i)
          gl_lds16(e_ws + s1 * 16384 + i * 2048 + tx * 8,
                   bbf + buf1 * 16384 + i * 2048 + w * 512);
      } else {
        const int cl = tx & 127, kh2 = tx >> 7;
        const float* src = e + (size_t)((s1 >> 2) * 128 + cl) * D_DIM + (s1 & 3) * 64;
        #pragma unroll
        for (int ch8 = 0; ch8 < 4; ++ch8) {
          int kd0 = kh2 * 32 + ch8 * 8;
          float4 v0 = *(const float4*)(src + kd0);
          float4 v1 = *(const float4*)(src + kd0 + 4);
          float vv[8] = {v0.x, v0.y, v0.z, v0.w, v1.x, v1.y, v1.z, v1.w};
          unsigned short h8[8], l8[8];
          #pragma unroll
          for (int j = 0; j < 8; ++j) { h8[j] = f2bf(vv[j]); l8[j] = f2bf(vv[j] - bf2f(h8[j])); }
          int slot = (kd0 >> 3) ^ (cl & 7);
          *(bf16x8*)&bbf[buf1 * 16384 + cl * 64 + slot * 8] = *(bf16x8*)h8;
          *(bf16x8*)&bbf[buf1 * 16384 + 8192 + cl * 64 + slot * 8] = *(bf16x8*)l8;
        }
      }
    }
    if (USE_WS) {
      if (s < 15) asm volatile("s_waitcnt vmcnt(8)");
      else        asm volatile("s_waitcnt vmcnt(0)");
    }
    __syncthreads();  // stage-s loads visible everywhere; x/b writes drained

    const int kq = s & 3, buf = s & 1;
    #pragma unroll
    for (int chunk2 = 0; chunk2 < 2; ++chunk2) {
      bf16x8 ah[4], al[4], bh[2], bl[2];
      #pragma unroll
      for (int mi = 0; mi < 4; ++mi) {
        int rl = mi * 16 + c;
        int chunkA = kq * 8 + chunk2 * 4 + g;
        int slot = (chunkA & 24) | ((chunkA ^ rl) & 7);
        ah[mi] = *(const bf16x8*)&xh[rl * 256 + slot * 8];
        al[mi] = *(const bf16x8*)&xl[rl * 256 + slot * 8];
      }
      #pragma unroll
      for (int nj = 0; nj < 2; ++nj) {
        int cr = w * 32 + nj * 16 + c;
        int slot = (chunk2 * 4 + g) ^ (cr & 7);
        bh[nj] = *(const bf16x8*)&bbf[buf * 16384 + cr * 64 + slot * 8];
        bl[nj] = *(const bf16x8*)&bbf[buf * 16384 + 8192 + cr * 64 + slot * 8];
      }
      // 3-product split: hh, hl, lh (acc-dependency distance 8)
      #pragma unroll
      for (int mi = 0; mi < 4; ++mi)
        #pragma unroll
        for (int nj = 0; nj < 2; ++nj)
          acc[mi][nj] = __builtin_amdgcn_mfma_f32_16x16x32_bf16(ah[mi], bh[nj], acc[mi][nj], 0, 0, 0);
      #pragma unroll
      for (int mi = 0; mi < 4; ++mi)
        #pragma unroll
        for (int nj = 0; nj < 2; ++nj)
          acc[mi][nj] = __builtin_amdgcn_mfma_f32_16x16x32_bf16(ah[mi], bl[nj], acc[mi][nj], 0, 0, 0);
      #pragma unroll
      for (int mi = 0; mi < 4; ++mi)
        #pragma unroll
        for (int nj = 0; nj < 2; ++nj)
          acc[mi][nj] = __builtin_amdgcn_mfma_f32_16x16x32_bf16(al[mi], bh[nj], acc[mi][nj], 0, 0, 0);
    }

    if (kq == 3) {  // fold this code-quarter into running argmin + margin count
      int cq = s >> 2;
      float nrm[2];
      #pragma unroll
      for (int nj = 0; nj < 2; ++nj) nrm[nj] = nlds[cq * 128 + w * 32 + nj * 16 + c];
      #pragma unroll
      for (int mi = 0; mi < 4; ++mi)
        #pragma unroll
        for (int q = 0; q < 4; ++q) {
          float m = mrow[mi][q]; int id = irow[mi][q]; int cn = crow[mi][q];
          #pragma unroll
          for (int nj = 0; nj < 2; ++nj) {
            float sv = fmaf(-2.f, acc[mi][nj][q], nrm[nj]);
            int code = cq * 128 + w * 32 + nj * 16 + c;
            if (sv < m - FMARGIN)       { m = sv; id = code; cn = 1; }
            else if (sv < m)            { m = sv; id = code; cn++; }
            else if (sv <= m + FMARGIN) cn++;
          }
          mrow[mi][q] = m; irow[mi][q] = id; crow[mi][q] = cn;
        }
      #pragma unroll
      for (int mi = 0; mi < 4; ++mi)
        #pragma unroll
        for (int nj = 0; nj < 2; ++nj) acc[mi][nj] = (f32x4){0.f, 0.f, 0.f, 0.f};
    }
    __syncthreads();  // everyone done reading buf before it's overwritten
  }

  // cross-lane reduce within 16-lane groups (codes across c)
  #pragma unroll
  for (int mi = 0; mi < 4; ++mi)
    #pragma unroll
    for (int q = 0; q < 4; ++q) {
      float m = mrow[mi][q]; int id = irow[mi][q]; int cn = crow[mi][q];
      #pragma unroll
      for (int off = 1; off < 16; off <<= 1) {
        float om = __shfl_xor(m, off, 64);
        int oi = __shfl_xor(id, off, 64);
        int oc = __shfl_xor(cn, off, 64);
        int nc;
        if (om < m - FMARGIN) nc = oc;
        else if (m < om - FMARGIN) nc = cn;
        else nc = cn + oc;
        if (om < m || (om == m && oi < id)) { m = om; id = oi; }
        cn = nc;
      }
      if (c == 0) {
        int rl = mi * 16 + g * 4 + q;
        wmin[w][rl] = m; wid[w][rl] = id; wcnt[w][rl] = cn;
      }
    }
  __syncthreads();
  // merge 4 waves (disjoint code sets) per row
  if (tx < 64) {
    float m = wmin[0][tx]; int id = wid[0][tx]; int cn = wcnt[0][tx];
    #pragma unroll
    for (int w2 = 1; w2 < 4; ++w2) {
      float m2 = wmin[w2][tx]; int i2 = wid[w2][tx]; int c2 = wcnt[w2][tx];
      int nc = (fabsf(m - m2) <= FMARGIN) ? (cn + c2) : ((m2 < m) ? c2 : cn);
      if (m2 < m || (m2 == m && i2 < id)) { m = m2; id = i2; }
      cn = nc;
    }
    widx[tx] = id; rmin[tx] = m;
    out_idx[(size_t)blk * 64 + tx] = (float)id;
    if (cn >= 2) atomicOr(&lflag[tx >> 5], 1u << (tx & 31));
  }
  __syncthreads();
  if (tx < 2) bitmap[blk * 2 + tx] = lflag[tx];

  // fused q-write: wave w writes rows [w*16, w*16+16)
  #pragma unroll 4
  for (int i = 0; i < 16; ++i) {
    int row = w * 16 + i;
    int k = widx[row];
    float4 ev = *(const float4*)(e + (size_t)k * D_DIM + lane * 4);
    *(float4*)(out_q + ((size_t)blk * 64 + row) * D_DIM + lane * 4) = ev;
  }

  // loss partial: sum(x^2) + sum(row min scores)
  double dv = (double)xsum + ((tx < 64) ? (double)rmin[tx] : 0.0);
  #pragma unroll
  for (int o = 32; o > 0; o >>= 1) dv += __shfl_down(dv, o, 64);
  if (lane == 0) dred[w] = dv;
  __syncthreads();
  if (tx == 0) bsums[blk] = (dred[0] + dred[1]) + (dred[2] + dred[3]);
}

// Exact fp32 rescan (numpy-replica, validated round 4) for flagged rows.
__global__ __launch_bounds__(256) void vq_fixup(
    const float* __restrict__ x, const float* __restrict__ e,
    const float* __restrict__ norms, const unsigned* __restrict__ bitmap,
    float* __restrict__ out_q, float* __restrict__ out_idx) {
  __shared__ float xrow[16][257];
  __shared__ float elds[64][257];
  __shared__ float xxr[16];
  __shared__ int list[256];
  __shared__ int lcount;
  __shared__ float redm[16][16];
  __shared__ int   redi[16][16];
  __shared__ int   wk[16];

  const int bidx = blockIdx.x, tx = threadIdx.x;
  if (tx == 0) {
    int cnt = 0;
    for (int wi = 0; wi < 8; ++wi) {
      unsigned u = bitmap[bidx * 8 + wi];
      while (u) {
        int bit = __ffs(u) - 1;
        list[cnt++] = bidx * 256 + wi * 32 + bit;
        u &= u - 1;
      }
    }
    lcount = cnt;
  }
  __syncthreads();
  const int nf = lcount;
  const int ri = tx >> 4, dpart = tx & 15;
  const int r = tx & 15, cg = tx >> 4;

  for (int g0 = 0; g0 < nf; g0 += 16) {
    int R = min(16, nf - g0);
    if (ri < R) {
      int n = list[g0 + ri];
      int b2 = n >> 11, t = n & 2047;
      for (int j = 0; j < 16; ++j) {
        int d = dpart * 16 + j;
        xrow[ri][d] = x[((size_t)(b2 * 256 + d)) * 2048 + t];
      }
    }
    __syncthreads();
    if (tx < R) {  // numpy-pairwise ||x||^2
      float res[2];
      #pragma unroll
      for (int h = 0; h < 2; ++h) {
        float r8[8];
        #pragma unroll
        for (int j = 0; j < 8; ++j) { float a = xrow[tx][h * 128 + j]; r8[j] = __fmul_rn(a, a); }
        for (int i = 8; i < 128; i += 8)
          #pragma unroll
          for (int j = 0; j < 8; ++j) { float a = xrow[tx][h * 128 + i + j]; r8[j] = __fadd_rn(r8[j], __fmul_rn(a, a)); }
        res[h] = comb8(r8);
      }
      xxr[tx] = __fadd_rn(res[0], res[1]);
    }
    float m = 3.4e38f; int mi_ = 0;
    for (int ch = 0; ch < 8; ++ch) {
      __syncthreads();
      {
        int er = tx >> 2, qd = tx & 3;
        for (int j = 0; j < 16; ++j)
          *(float4*)&elds[er][qd * 64 + j * 4] =
              *(const float4*)(e + (size_t)(ch * 64 + er) * 256 + qd * 64 + j * 4);
      }
      __syncthreads();
      if (r < R) {
        // 4 independent exact sequential-d chains (bit-identical per code)
        float a0 = 0.f, a1 = 0.f, a2 = 0.f, a3 = 0.f;
        const float* xr_ = &xrow[r][0];
        const float* e0 = &elds[cg * 4 + 0][0];
        const float* e1 = &elds[cg * 4 + 1][0];
        const float* e2 = &elds[cg * 4 + 2][0];
        const float* e3 = &elds[cg * 4 + 3][0];
        for (int d = 0; d < 256; ++d) {
          float xv = xr_[d];
          a0 = __fmaf_rn(xv, e0[d], a0);
          a1 = __fmaf_rn(xv, e1[d], a1);
          a2 = __fmaf_rn(xv, e2[d], a2);
          a3 = __fmaf_rn(xv, e3[d], a3);
        }
        float av[4] = {a0, a1, a2, a3};
        #pragma unroll
        for (int j = 0; j < 4; ++j) {
          int k = ch * 64 + cg * 4 + j;
          float t1 = __fadd_rn(xxr[r], norms[k]);
          float sv = t1 - 2.0f * av[j];
          if (sv < m) { m = sv; mi_ = k; }
        }
      }
    }
    redm[r][cg] = m; redi[r][cg] = mi_;
    __syncthreads();
    if (tx < R) {
      float mm = redm[tx][0]; int ii = redi[tx][0];
      for (int q2 = 1; q2 < 16; ++q2) {
        float s2 = redm[tx][q2]; int s2i = redi[tx][q2];
        if (s2 < mm || (s2 == mm && s2i < ii)) { mm = s2; ii = s2i; }
      }
      int n = list[g0 + tx];
      out_idx[n] = (float)ii;
      wk[tx] = ii;
    }
    __syncthreads();
    if (ri < R) {
      int n = list[g0 + ri];
      int k = wk[ri];
      for (int j = 0; j < 16; ++j) {
        int d = dpart * 16 + j;
        out_q[(size_t)n * 256 + d] = e[(size_t)k * 256 + d];
      }
    }
    __syncthreads();
  }
}

__global__ __launch_bounds__(256) void vq_final(const double* __restrict__ bs,
                                                float* __restrict__ out_loss) {
  __shared__ double sred[4];
  int t = threadIdx.x;
  double s = 0.0;
  for (int i = t; i < 2048; i += 256) s += bs[i];
  #pragma unroll
  for (int o = 32; o > 0; o >>= 1) s += __shfl_down(s, o, 64);
  if ((t & 63) == 0) sred[t >> 6] = s;
  __syncthreads();
  if (t == 0)
    out_loss[0] = (float)(0.25 * (((sred[0] + sred[1]) + (sred[2] + sred[3])) / (double)Q_ELEMS));
}

extern "C" void kernel_launch(void* const* d_in, const int* in_sizes, int n_in,
                              void* d_out, int out_size, void* d_ws, size_t ws_size,
                              hipStream_t stream) {
  const float* x = (const float*)d_in[0];
  const float* e = (const float*)d_in[1];
  float* out = (float*)d_out;
  float* out_q = out;
  float* out_loss = out + Q_ELEMS;
  float* out_idx = out + Q_ELEMS + 1;

  char* ws = (char*)d_ws;
  float* norms = (float*)ws;
  double* bsums = (double*)(ws + 2048);
  unsigned* bitmap = (unsigned*)(ws + 20480);
  unsigned short* e_ws = (unsigned short*)(ws + 36864);
  int use_ws = (ws_size >= 561152) ? 1 : 0;

  vq_prep<<<K_CODES, 256, 0, stream>>>(e, norms, e_ws, bitmap, use_ws);
  if (use_ws)
    vq_main<1><<<N_ROWS / 64, 256, 0, stream>>>(x, e, norms, e_ws, out_q, out_idx, bsums, bitmap);
  else
    vq_main<0><<<N_ROWS / 64, 256, 0, stream>>>(x, e, norms, e_ws, out_q, out_idx, bsums, bitmap);
  vq_fixup<<<512, 256, 0, stream>>>(x, e, norms, bitmap, out_q, out_idx);
  vq_final<<<1, 256, 0, stream>>>(bsums, out_loss);
}